// Round 9
// baseline (136.446 us; speedup 1.0000x reference)
//
#include <hip/hip_runtime.h>

#define VQ_EPS    1e-12f
#define VQ_WINDOW 0.01f     // >= ~10 sigma of the bf16 score error; proven R6/R8 (absmax 0)
#define VQ_CAP    12

typedef short bf16x8 __attribute__((ext_vector_type(8)));   // 8 bf16 bit-patterns = 4 VGPRs
typedef float f32x4  __attribute__((ext_vector_type(4)));

static __device__ __forceinline__ unsigned short f2bf(float f) {
    unsigned u = __float_as_uint(f);
    u += 0x7fffu + ((u >> 16) & 1u);     // RNE
    return (unsigned short)(u >> 16);
}

// Order-preserving float->uint map (handles negative exact scores).
static __device__ __forceinline__ unsigned f2ord(float f) {
    unsigned b = __float_as_uint(f);
    return (b & 0x80000000u) ? ~b : (b | 0x80000000u);
}

// Prep kernel: normalize codebook rows (fp32, mirrors F.normalize), emit:
//   cbn  [512][64] fp32      -- exact rescore + codes-gather epilogue
//   cbB  [32 ntile][2 kstep][64 lane][8] bf16 -- B-fragment-linear for
//        mfma_f32_16x16x32_bf16 (layout proven correct R5-R8)
//   kn2  [512] fp32          -- sum(cbn^2) AFTER normalization (reference rounding)
//   kn2p [512] fp32          -- kn2 + 2.0f (keeps approx scores > 0 for uint packing)
__global__ __launch_bounds__(64) void cb_prep_kernel(const float* __restrict__ cb,
                                                     float* __restrict__ cbn,
                                                     unsigned short* __restrict__ cbB,
                                                     float* __restrict__ kn2,
                                                     float* __restrict__ kn2p) {
    const int k = blockIdx.x;       // 512 codes
    const int c = threadIdx.x;      // 64 channels
    float v = cb[k * 64 + c];
    float s = v * v;
    #pragma unroll
    for (int off = 32; off > 0; off >>= 1) s += __shfl_xor(s, off, 64);
    float n = sqrtf(s);
    float cn = v / fmaxf(n, VQ_EPS);
    cbn[k * 64 + c] = cn;

    const int ntile = k >> 4, col = k & 15;
    const int ks = c >> 5, quad = (c >> 3) & 3, j = c & 7;
    cbB[(((ntile * 2 + ks) * 64) + quad * 16 + col) * 8 + j] = f2bf(cn);

    float s2 = cn * cn;
    #pragma unroll
    for (int off = 32; off > 0; off >>= 1) s2 += __shfl_xor(s2, off, 64);
    if (c == 0) { kn2[k] = s2; kn2p[k] = s2 + 2.0f; }
}

// Main kernel: 2048 blocks x 256 thr; block = one (b,h) row of 64 pixels.
// NO LDS codebook: B-fragments stream from global (cbB is 64 KB, L2-resident;
// gBf[tile*64+lane] is 1 KB contiguous per wave -> perfect coalescing). LDS
// holds only per-pixel candidate state (~1.3 KB) -> occupancy VGPR-capped
// (~5 waves/SIMD) instead of LDS-capped (2). Numerics identical to R8:
// MFMA pass1 approx argmin (packed key), bit-identical pass2 collects
// candidates within VQ_WINDOW, per-lane exact fp32 rescore via 64-bit LDS
// atomicMin. All shfls in uniform code; barriers kept per the R8 safe recipe.
__global__ __launch_bounds__(256) void vq_mfma_kernel(const float* __restrict__ x,
                                                      const float* __restrict__ cbn,
                                                      const unsigned short* __restrict__ cbB,
                                                      const float* __restrict__ kn2,
                                                      const float* __restrict__ kn2p,
                                                      float* __restrict__ codes,
                                                      float* __restrict__ idxout) {
    __shared__ int    scnt[64];
    __shared__ int    slist[64][VQ_CAP];
    __shared__ unsigned long long spack[64];

    const int t    = threadIdx.x;
    const int lane = t & 63;
    const int wid  = t >> 6;
    const int col  = lane & 15;
    const int quad = lane >> 4;
    const int wpix = wid * 16 + col;      // col-group's pixel (w coordinate)

    const int rowid = blockIdx.x;         // 0..2047 = (b,h)
    const int b = rowid >> 6;
    const int h = rowid & 63;
    const float* xblk = x + ((size_t)b << 18) + (h << 6);   // + c*4096 + w

    if (quad == 0) { scnt[wpix] = 0; spack[wpix] = 0xFFFFFFFFFFFFFFFFull; }

    // ---- A fragments: 16 channels of this lane's pixel, from global ----
    float xv[16];
    #pragma unroll
    for (int ks = 0; ks < 2; ++ks)
        #pragma unroll
        for (int j = 0; j < 8; ++j)
            xv[ks * 8 + j] = xblk[(size_t)(ks * 32 + quad * 8 + j) * 4096 + wpix];

    float ssp = 0.0f;
    #pragma unroll
    for (int i = 0; i < 16; ++i) ssp = fmaf(xv[i], xv[i], ssp);
    ssp += __shfl_xor(ssp, 16);      // uniform code: all 64 lanes execute
    ssp += __shfl_xor(ssp, 32);
    const float m2a = -2.0f * (1.0f / fmaxf(sqrtf(ssp), VQ_EPS));
    float m2r[4];
    #pragma unroll
    for (int r = 0; r < 4; ++r) m2r[r] = __shfl(m2a, quad * 4 + r);  // uniform
    const float m2P = __shfl(m2a, lane >> 2);   // uniform: m2 of rescore pixel

    bf16x8 afrag[2];
    #pragma unroll
    for (int ks = 0; ks < 2; ++ks)
        #pragma unroll
        for (int j = 0; j < 8; ++j)
            ((unsigned short*)&afrag[ks])[j] = f2bf(xv[ks * 8 + j]);

    const bf16x8* gBf = (const bf16x8*)cbB;

    // ---- pass 1: MFMA scan, packed running approx argmin ----
    unsigned run[4] = {0xFFFFFFFFu, 0xFFFFFFFFu, 0xFFFFFFFFu, 0xFFFFFFFFu};
    #pragma unroll 4
    for (int nt = 0; nt < 32; ++nt) {
        bf16x8 b0 = gBf[(nt * 2 + 0) * 64 + lane];     // 1 KB coalesced, L2-hot
        bf16x8 b1 = gBf[(nt * 2 + 1) * 64 + lane];
        f32x4 c = {0.0f, 0.0f, 0.0f, 0.0f};
        c = __builtin_amdgcn_mfma_f32_16x16x32_bf16(afrag[0], b0, c, 0, 0, 0);
        c = __builtin_amdgcn_mfma_f32_16x16x32_bf16(afrag[1], b1, c, 0, 0, 0);
        const float    kn   = kn2p[nt * 16 + col];     // 64 B broadcast-4, L1-hot
        const unsigned kidx = (unsigned)(nt * 16 + col);
        #pragma unroll
        for (int r = 0; r < 4; ++r) {
            float s = fmaf(m2r[r], c[r], kn);          // in (~0.6, 5.2) -> uint-orderable
            unsigned key = (__float_as_uint(s) & 0xFFFFFE00u) | kidx;
            run[r] = min(run[r], key);
        }
    }

    // ---- threshold: cross-lane min within each 16-lane col group (uniform) ----
    float thr[4];
    #pragma unroll
    for (int r = 0; r < 4; ++r) {
        unsigned v = run[r];
        v = min(v, (unsigned)__shfl_xor((int)v, 1));
        v = min(v, (unsigned)__shfl_xor((int)v, 2));
        v = min(v, (unsigned)__shfl_xor((int)v, 4));
        v = min(v, (unsigned)__shfl_xor((int)v, 8));
        thr[r] = __uint_as_float(v & 0xFFFFFE00u) + VQ_WINDOW;
    }

    // ---- pass 2: bit-identical recompute, collect candidates ----
    #pragma unroll 4
    for (int nt = 0; nt < 32; ++nt) {
        bf16x8 b0 = gBf[(nt * 2 + 0) * 64 + lane];
        bf16x8 b1 = gBf[(nt * 2 + 1) * 64 + lane];
        f32x4 c = {0.0f, 0.0f, 0.0f, 0.0f};
        c = __builtin_amdgcn_mfma_f32_16x16x32_bf16(afrag[0], b0, c, 0, 0, 0);
        c = __builtin_amdgcn_mfma_f32_16x16x32_bf16(afrag[1], b1, c, 0, 0, 0);
        const float kn   = kn2p[nt * 16 + col];
        const int   kidx = nt * 16 + col;
        #pragma unroll
        for (int r = 0; r < 4; ++r) {
            float s = fmaf(m2r[r], c[r], kn);
            if (s <= thr[r]) {
                int pix = wid * 16 + quad * 4 + r;     // wave-owned pixel
                int pos = atomicAdd(&scnt[pix], 1);
                if (pos < VQ_CAP) slist[pix][pos] = kidx;
            }
        }
    }
    __syncthreads();   // B1: candidates visible (R8 safe recipe)

    // ---- exact fp32 rescore: 4 lanes/pixel, per-lane only (no shfl here) ----
    {
        const int P   = wid * 16 + (lane >> 2);    // this lane's rescore pixel
        const int sub = lane & 3;
        const int cnt = scnt[P];
        if (cnt > 1) {
            const float* xp = xblk + P;
            if (cnt <= VQ_CAP) {
                for (int i = sub; i < cnt; i += 4) {
                    const int k = slist[P][i];
                    const float* cr = cbn + (size_t)k * 64;
                    float dot = 0.0f;
                    #pragma unroll 8
                    for (int c = 0; c < 64; ++c)
                        dot = fmaf(xp[(size_t)c * 4096], cr[c], dot);  // R1 order
                    float s = fmaf(m2P, dot, kn2[k]);
                    unsigned long long key =
                        ((unsigned long long)f2ord(s) << 32) | (unsigned)k;
                    atomicMin(&spack[P], key);
                }
            } else {   // statistically dead overflow: exact scan of all codes
                for (int k = sub; k < 512; k += 4) {
                    const float* cr = cbn + (size_t)k * 64;
                    float dot = 0.0f;
                    #pragma unroll 8
                    for (int c = 0; c < 64; ++c)
                        dot = fmaf(xp[(size_t)c * 4096], cr[c], dot);
                    float s = fmaf(m2P, dot, kn2[k]);
                    unsigned long long key =
                        ((unsigned long long)f2ord(s) << 32) | (unsigned)k;
                    atomicMin(&spack[P], key);
                }
            }
        }
    }
    __syncthreads();   // B2: rescore results visible

    // ---- winner (packed key ties break to smallest k; cnt==1 fast path) ----
    const int cntw = scnt[wpix];
    const int bk = (cntw == 1) ? slist[wpix][0]
                               : (int)(spack[wpix] & 0xFFFFFFFFull);

    if (quad == 0) idxout[rowid * 64 + wpix] = (float)bk;

    // ---- epilogue: codes[b, :, h, wpix] = cbn[bk, :]; lane writes channels
    //      quad*16 .. quad*16+15 ----
    {
        const float4* crow = (const float4*)(cbn + (size_t)bk * 64) + quad * 4;
        float* cp = codes + ((size_t)b << 18) + (h << 6) + wpix;
        #pragma unroll
        for (int q = 0; q < 4; ++q) {
            float4 v = crow[q];
            const int c0 = quad * 16 + q * 4;
            cp[(size_t)(c0 + 0) * 4096] = v.x;
            cp[(size_t)(c0 + 1) * 4096] = v.y;
            cp[(size_t)(c0 + 2) * 4096] = v.z;
            cp[(size_t)(c0 + 3) * 4096] = v.w;
        }
    }
}

extern "C" void kernel_launch(void* const* d_in, const int* in_sizes, int n_in,
                              void* d_out, int out_size, void* d_ws, size_t ws_size,
                              hipStream_t stream) {
    const float* x  = (const float*)d_in[0];   // [32,64,64,64] fp32
    const float* cb = (const float*)d_in[1];   // [512,64] fp32

    float*          cbn  = (float*)d_ws;                       // 128 KB
    unsigned short* cbB  = (unsigned short*)(cbn + 512 * 64);  // 64 KB (frag-linear bf16)
    float*          kn2  = (float*)(cbB + 32768);              // 2 KB
    float*          kn2p = kn2 + 512;                          // 2 KB

    float* codes  = (float*)d_out;                             // 32*64*64*64 floats
    float* idxout = codes + (size_t)32 * 64 * 64 * 64;         // 131072 floats

    cb_prep_kernel<<<512, 64, 0, stream>>>(cb, cbn, cbB, kn2, kn2p);
    vq_mfma_kernel<<<2048, 256, 0, stream>>>(x, cbn, cbB, kn2, kn2p, codes, idxout);
}